// Round 1
// baseline (536.653 us; speedup 1.0000x reference)
//
#include <hip/hip_runtime.h>

#define BB    8
#define LSEQ  4096
#define DD    4096
#define EE    8
#define RR    16
#define KK    2
#define LORA_SCALE (1.0f / 16.0f)   // ALPHA / R
#define LN_EPS 1e-5f

__device__ __forceinline__ float wave_sum(float v) {
#pragma unroll
    for (int off = 32; off > 0; off >>= 1)
        v += __shfl_down(v, off, 64);
    return v;
}

// ---------------------------------------------------------------------------
// Kernel 1: partial column sums of x over a slice of L.
// grid = (DD/1024, BB, nslice), block = 256. Each thread owns one float4 lane
// of a 1024-float D-chunk and accumulates over rows_per_slice rows.
// Deterministic (no atomics): partials land in ws[slice][b][d].
// ---------------------------------------------------------------------------
__global__ __launch_bounds__(256) void colsum_kernel(
    const float4* __restrict__ x, float4* __restrict__ partial, int rows_per_slice)
{
    const int tid = threadIdx.x;
    const int dchunk = blockIdx.x;          // 0..DD/1024-1
    const int b = blockIdx.y;               // 0..BB-1
    const int sl = blockIdx.z;              // 0..nslice-1
    const int d4 = dchunk * 256 + tid;      // float4 index within a row
    const size_t row0 = (size_t)b * LSEQ + (size_t)sl * rows_per_slice;
    const float4* p = x + row0 * (DD / 4) + d4;

    float4 acc = make_float4(0.f, 0.f, 0.f, 0.f);
    for (int l = 0; l < rows_per_slice; ++l) {
        float4 xv = p[(size_t)l * (DD / 4)];
        acc.x += xv.x; acc.y += xv.y; acc.z += xv.z; acc.w += xv.w;
    }
    partial[((size_t)sl * BB + b) * (DD / 4) + d4] = acc;
}

// ---------------------------------------------------------------------------
// Kernel 2: router (top-2 softmax) + LoRA delta, one block per batch element.
// ---------------------------------------------------------------------------
__global__ __launch_bounds__(256) void router_delta_kernel(
    const float* __restrict__ partial, int nslice,
    const float* __restrict__ gate_w, const float* __restrict__ gate_b,
    const float* __restrict__ A_w, const float* __restrict__ B_w,
    float* __restrict__ delta)
{
    __shared__ float hbuf[DD];              // 16 KB: pooled hidden state
    __shared__ float red[KK * RR * 4];      // cross-wave reduce scratch (128)
    __shared__ float zbuf[KK * RR];
    __shared__ int   sel[KK];
    __shared__ float wsel[KK];

    const int b = blockIdx.x;
    const int tid = threadIdx.x;
    const int lane = tid & 63;
    const int wid = tid >> 6;

    // h[d] = (1/L) * sum over slices of partial
    for (int d = tid; d < DD; d += 256) {
        float s = 0.f;
        for (int sl = 0; sl < nslice; ++sl)
            s += partial[((size_t)sl * BB + b) * DD + d];
        hbuf[d] = s * (1.0f / LSEQ);
    }
    __syncthreads();

    // logits[e] = h . gate_w[e] + gate_b[e]
    float lacc[EE];
#pragma unroll
    for (int e = 0; e < EE; ++e) lacc[e] = 0.f;
    for (int d = tid; d < DD; d += 256) {
        float hd = hbuf[d];
#pragma unroll
        for (int e = 0; e < EE; ++e) lacc[e] += hd * gate_w[e * DD + d];
    }
#pragma unroll
    for (int e = 0; e < EE; ++e) {
        float s = wave_sum(lacc[e]);
        if (lane == 0) red[e * 4 + wid] = s;
    }
    __syncthreads();
    if (tid == 0) {
        float lg[EE];
#pragma unroll
        for (int e = 0; e < EE; ++e)
            lg[e] = red[e * 4] + red[e * 4 + 1] + red[e * 4 + 2] + red[e * 4 + 3] + gate_b[e];
        int i0 = 0;
        for (int e = 1; e < EE; ++e) if (lg[e] > lg[i0]) i0 = e;   // strict > : lowest index on ties
        int i1 = (i0 == 0) ? 1 : 0;
        for (int e = 0; e < EE; ++e) if (e != i0 && lg[e] > lg[i1]) i1 = e;
        float e1 = __expf(lg[i1] - lg[i0]);
        float inv = 1.0f / (1.0f + e1);
        sel[0] = i0; sel[1] = i1;
        wsel[0] = inv; wsel[1] = e1 * inv;
    }
    __syncthreads();

    // z[k][r] = sum_d A_w[sel_k][r][d] * h[d]
    float zacc[KK][RR];
#pragma unroll
    for (int k = 0; k < KK; ++k)
#pragma unroll
        for (int r = 0; r < RR; ++r) zacc[k][r] = 0.f;
    const float* A0 = A_w + (size_t)sel[0] * RR * DD;
    const float* A1 = A_w + (size_t)sel[1] * RR * DD;
    for (int d = tid; d < DD; d += 256) {
        float hd = hbuf[d];
#pragma unroll
        for (int r = 0; r < RR; ++r) zacc[0][r] += hd * A0[r * DD + d];
#pragma unroll
        for (int r = 0; r < RR; ++r) zacc[1][r] += hd * A1[r * DD + d];
    }
#pragma unroll
    for (int k = 0; k < KK; ++k)
#pragma unroll
        for (int r = 0; r < RR; ++r) {
            float s = wave_sum(zacc[k][r]);
            if (lane == 0) red[(k * RR + r) * 4 + wid] = s;
        }
    __syncthreads();
    if (tid < KK * RR)
        zbuf[tid] = red[tid * 4] + red[tid * 4 + 1] + red[tid * 4 + 2] + red[tid * 4 + 3];
    __syncthreads();

    // delta[d] = scale * sum_k w_k * sum_r B_w[sel_k][d][r] * z[k][r]
    const float w0 = wsel[0], w1 = wsel[1];
    const float* B0 = B_w + (size_t)sel[0] * DD * RR;
    const float* B1 = B_w + (size_t)sel[1] * DD * RR;
    for (int d = tid; d < DD; d += 256) {
        float s0 = 0.f, s1 = 0.f;
#pragma unroll
        for (int r = 0; r < RR; ++r) {
            s0 += B0[d * RR + r] * zbuf[r];
            s1 += B1[d * RR + r] * zbuf[RR + r];
        }
        delta[(size_t)b * DD + d] = LORA_SCALE * (w0 * s0 + w1 * s1);
    }
}

// ---------------------------------------------------------------------------
// Kernel 3: y = LN(x + delta[b]) * gamma + beta. One block per (b,l) row.
// 256 threads x 16 floats held in registers; single global read of the row.
// ---------------------------------------------------------------------------
__global__ __launch_bounds__(256) void resid_ln_kernel(
    const float4* __restrict__ x, const float4* __restrict__ delta,
    const float4* __restrict__ gamma, const float4* __restrict__ beta,
    float4* __restrict__ out)
{
    __shared__ float redsum[4], redsq[4];
    __shared__ float s_mean, s_rstd;
    const int row = blockIdx.x;             // b * LSEQ + l
    const int b = row >> 12;                // LSEQ = 4096
    const int tid = threadIdx.x;
    const int lane = tid & 63, wid = tid >> 6;
    const float4* xr = x + (size_t)row * (DD / 4);
    const float4* dr = delta + (size_t)b * (DD / 4);

    float4 v[4];
    float sum = 0.f, sq = 0.f;
#pragma unroll
    for (int i = 0; i < 4; ++i) {
        const int idx = tid + i * 256;
        float4 xv = xr[idx];
        float4 dv = dr[idx];
        xv.x += dv.x; xv.y += dv.y; xv.z += dv.z; xv.w += dv.w;
        v[i] = xv;
        sum += xv.x + xv.y + xv.z + xv.w;
        sq  += xv.x * xv.x + xv.y * xv.y + xv.z * xv.z + xv.w * xv.w;
    }
    float wsm = wave_sum(sum);
    float wsq = wave_sum(sq);
    if (lane == 0) { redsum[wid] = wsm; redsq[wid] = wsq; }
    __syncthreads();
    if (tid == 0) {
        float S = redsum[0] + redsum[1] + redsum[2] + redsum[3];
        float Q = redsq[0] + redsq[1] + redsq[2] + redsq[3];
        float mean = S * (1.0f / DD);
        float var = Q * (1.0f / DD) - mean * mean;
        s_mean = mean;
        s_rstd = rsqrtf(var + LN_EPS);
    }
    __syncthreads();
    const float mean = s_mean, rstd = s_rstd;
    float4* orow = out + (size_t)row * (DD / 4);
#pragma unroll
    for (int i = 0; i < 4; ++i) {
        const int idx = tid + i * 256;
        float4 gv = gamma[idx];
        float4 bv = beta[idx];
        float4 xv = v[i];
        float4 o;
        o.x = (xv.x - mean) * rstd * gv.x + bv.x;
        o.y = (xv.y - mean) * rstd * gv.y + bv.y;
        o.z = (xv.z - mean) * rstd * gv.z + bv.z;
        o.w = (xv.w - mean) * rstd * gv.w + bv.w;
        orow[idx] = o;
    }
}

extern "C" void kernel_launch(void* const* d_in, const int* in_sizes, int n_in,
                              void* d_out, int out_size, void* d_ws, size_t ws_size,
                              hipStream_t stream) {
    const float* x      = (const float*)d_in[0];
    const float* gate_w = (const float*)d_in[1];
    const float* gate_b = (const float*)d_in[2];
    const float* A_w    = (const float*)d_in[3];
    const float* B_w    = (const float*)d_in[4];
    const float* gamma  = (const float*)d_in[5];
    const float* beta   = (const float*)d_in[6];
    float* out = (float*)d_out;
    float* ws  = (float*)d_ws;

    const size_t bd = (size_t)BB * DD;
    // scratch: nslice*B*D partials + B*D delta (floats). Shrink nslice to fit ws.
    int nslice = 32;
    while (nslice > 1 && (size_t)(nslice + 1) * bd * sizeof(float) > ws_size)
        nslice >>= 1;
    float* partial = ws;
    float* delta   = ws + (size_t)nslice * bd;

    dim3 g1(DD / 1024, BB, nslice);
    colsum_kernel<<<g1, 256, 0, stream>>>(
        (const float4*)x, (float4*)partial, LSEQ / nslice);

    router_delta_kernel<<<BB, 256, 0, stream>>>(
        partial, nslice, gate_w, gate_b, A_w, B_w, delta);

    resid_ln_kernel<<<BB * LSEQ, 256, 0, stream>>>(
        (const float4*)x, (const float4*)delta,
        (const float4*)gamma, (const float4*)beta, (float4*)out);
}

// Round 2
// 377.054 us; speedup vs baseline: 1.4233x; 1.4233x over previous
//
#include <hip/hip_runtime.h>

#define BB    8
#define LSEQ  4096
#define DD    4096
#define EE    8
#define RR    16
#define KK    2
#define NSLICE_MAX 128
#define LORA_SCALE (1.0f / 16.0f)   // ALPHA / R
#define LN_EPS 1e-5f

typedef float f4 __attribute__((ext_vector_type(4)));

// butterfly: every lane ends with the full 64-lane sum
__device__ __forceinline__ float wave_sum(float v) {
#pragma unroll
    for (int off = 32; off > 0; off >>= 1)
        v += __shfl_xor(v, off, 64);
    return v;
}

// ---------------------------------------------------------------------------
// Kernel 1: partial column sums of x over a slice of L.
// grid = (BB, nslice), block = 256. Each block streams rows_per_slice
// CONSECUTIVE rows (contiguous 16KB each); thread owns 4 float4 columns.
// Deterministic (no atomics): partials land in ws[slice][b][d].
// ---------------------------------------------------------------------------
__global__ __launch_bounds__(256) void colsum_kernel(
    const f4* __restrict__ x, f4* __restrict__ partial, int rows_per_slice)
{
    const int tid = threadIdx.x;
    const int b = blockIdx.x;
    const int sl = blockIdx.y;
    const size_t row0 = (size_t)b * LSEQ + (size_t)sl * rows_per_slice;
    const f4* p = x + row0 * (DD / 4);

    f4 acc[4];
#pragma unroll
    for (int i = 0; i < 4; ++i) acc[i] = (f4)(0.f);

#pragma unroll 2
    for (int l = 0; l < rows_per_slice; ++l) {
        const f4* pr = p + (size_t)l * (DD / 4);
#pragma unroll
        for (int i = 0; i < 4; ++i) {
            f4 xv = __builtin_nontemporal_load(&pr[tid + i * 256]);
            acc[i] += xv;
        }
    }
    f4* dst = partial + ((size_t)sl * BB + b) * (DD / 4);
#pragma unroll
    for (int i = 0; i < 4; ++i) dst[tid + i * 256] = acc[i];
}

// ---------------------------------------------------------------------------
// Kernel 2: router (top-2 softmax) + LoRA delta, one 1024-thread block per b.
// ---------------------------------------------------------------------------
__global__ __launch_bounds__(1024) void router_delta_kernel(
    const float* __restrict__ partial, int nslice,
    const float* __restrict__ gate_w, const float* __restrict__ gate_b,
    const float* __restrict__ A_w, const float* __restrict__ B_w,
    float* __restrict__ delta)
{
    __shared__ float hbuf[DD];              // 16 KB pooled hidden state
    __shared__ float redl[EE * 16];
    __shared__ float lgbuf[EE];
    __shared__ float redz[KK * RR * 16];
    __shared__ float zbuf[KK * RR];
    __shared__ int   sel[KK];
    __shared__ float wsel[KK];

    const int b = blockIdx.x;
    const int tid = threadIdx.x;
    const int lane = tid & 63;
    const int wid = tid >> 6;               // 0..15

    // h[d] = (1/L) * sum over slices of partial
    for (int d = tid; d < DD; d += 1024) {
        float s = 0.f;
#pragma unroll 8
        for (int sl = 0; sl < nslice; ++sl)
            s += partial[((size_t)sl * BB + b) * DD + d];
        hbuf[d] = s * (1.0f / LSEQ);
    }
    __syncthreads();

    // logits[e] = h . gate_w[e] + gate_b[e]
    float lacc[EE];
#pragma unroll
    for (int e = 0; e < EE; ++e) lacc[e] = 0.f;
    for (int d = tid; d < DD; d += 1024) {
        float hd = hbuf[d];
#pragma unroll
        for (int e = 0; e < EE; ++e) lacc[e] += hd * gate_w[e * DD + d];
    }
#pragma unroll
    for (int e = 0; e < EE; ++e) {
        float s = wave_sum(lacc[e]);
        if (lane == 0) redl[e * 16 + wid] = s;
    }
    __syncthreads();
    if (tid < EE) {
        float s = 0.f;
#pragma unroll
        for (int w = 0; w < 16; ++w) s += redl[tid * 16 + w];
        lgbuf[tid] = s + gate_b[tid];
    }
    __syncthreads();
    if (tid == 0) {
        int i0 = 0;
        for (int e = 1; e < EE; ++e) if (lgbuf[e] > lgbuf[i0]) i0 = e;  // ties -> lowest idx
        int i1 = (i0 == 0) ? 1 : 0;
        for (int e = 0; e < EE; ++e) if (e != i0 && lgbuf[e] > lgbuf[i1]) i1 = e;
        float e1 = __expf(lgbuf[i1] - lgbuf[i0]);
        float inv = 1.0f / (1.0f + e1);
        sel[0] = i0; sel[1] = i1;
        wsel[0] = inv; wsel[1] = e1 * inv;
    }
    __syncthreads();

    // z[k][r] = sum_d A_w[sel_k][r][d] * h[d]
    float zacc[KK][RR];
#pragma unroll
    for (int k = 0; k < KK; ++k)
#pragma unroll
        for (int r = 0; r < RR; ++r) zacc[k][r] = 0.f;
    const float* A0 = A_w + (size_t)sel[0] * RR * DD;
    const float* A1 = A_w + (size_t)sel[1] * RR * DD;
    for (int d = tid; d < DD; d += 1024) {
        float hd = hbuf[d];
#pragma unroll
        for (int r = 0; r < RR; ++r) zacc[0][r] += hd * A0[r * DD + d];
#pragma unroll
        for (int r = 0; r < RR; ++r) zacc[1][r] += hd * A1[r * DD + d];
    }
#pragma unroll
    for (int k = 0; k < KK; ++k)
#pragma unroll
        for (int r = 0; r < RR; ++r) {
            float s = wave_sum(zacc[k][r]);
            if (lane == 0) redz[(k * RR + r) * 16 + wid] = s;
        }
    __syncthreads();
    if (tid < KK * RR) {
        float s = 0.f;
#pragma unroll
        for (int w = 0; w < 16; ++w) s += redz[tid * 16 + w];
        zbuf[tid] = s;
    }
    __syncthreads();

    // delta[d] = scale * sum_k w_k * sum_r B_w[sel_k][d][r] * z[k][r]
    const float w0 = wsel[0], w1 = wsel[1];
    const float* B0 = B_w + (size_t)sel[0] * DD * RR;
    const float* B1 = B_w + (size_t)sel[1] * DD * RR;
    for (int d = tid; d < DD; d += 1024) {
        float s0 = 0.f, s1 = 0.f;
#pragma unroll
        for (int r = 0; r < RR; ++r) {
            s0 += B0[d * RR + r] * zbuf[r];
            s1 += B1[d * RR + r] * zbuf[RR + r];
        }
        delta[(size_t)b * DD + d] = LORA_SCALE * (w0 * s0 + w1 * s1);
    }
}

// ---------------------------------------------------------------------------
// Kernel 3: y = LN(x + delta[b]) * gamma + beta. ONE WAVE PER ROW.
// 64 lanes x 16 float4 in registers; butterfly reduce; no LDS, no barriers.
// grid = BB*LSEQ/4 blocks of 256 threads (4 rows per block).
// ---------------------------------------------------------------------------
__global__ __launch_bounds__(256) void resid_ln_kernel(
    const f4* __restrict__ x, const f4* __restrict__ delta,
    const f4* __restrict__ gamma, const f4* __restrict__ beta,
    f4* __restrict__ out)
{
    const int tid = threadIdx.x;
    const int lane = tid & 63, wid = tid >> 6;
    const int row = blockIdx.x * 4 + wid;   // b * LSEQ + l
    const int b = row >> 12;                // LSEQ = 4096
    const f4* xr = x + (size_t)row * (DD / 4);
    const f4* dr = delta + (size_t)b * (DD / 4);

    f4 v[16];
    float sum = 0.f, sq = 0.f;
#pragma unroll
    for (int i = 0; i < 16; ++i) {
        const int idx = lane + i * 64;
        f4 xv = __builtin_nontemporal_load(&xr[idx]);
        f4 dv = dr[idx];
        xv += dv;
        v[i] = xv;
        sum += xv.x + xv.y + xv.z + xv.w;
        sq  += xv.x * xv.x + xv.y * xv.y + xv.z * xv.z + xv.w * xv.w;
    }
    sum = wave_sum(sum);
    sq  = wave_sum(sq);
    const float mean = sum * (1.0f / DD);
    const float var  = sq * (1.0f / DD) - mean * mean;
    const float rstd = rsqrtf(var + LN_EPS);

    f4* orow = out + (size_t)row * (DD / 4);
#pragma unroll
    for (int i = 0; i < 16; ++i) {
        const int idx = lane + i * 64;
        f4 gv = gamma[idx];
        f4 bv = beta[idx];
        f4 xv = v[i];
        f4 o;
        o.x = (xv.x - mean) * rstd * gv.x + bv.x;
        o.y = (xv.y - mean) * rstd * gv.y + bv.y;
        o.z = (xv.z - mean) * rstd * gv.z + bv.z;
        o.w = (xv.w - mean) * rstd * gv.w + bv.w;
        __builtin_nontemporal_store(o, &orow[idx]);
    }
}

extern "C" void kernel_launch(void* const* d_in, const int* in_sizes, int n_in,
                              void* d_out, int out_size, void* d_ws, size_t ws_size,
                              hipStream_t stream) {
    const float* x      = (const float*)d_in[0];
    const float* gate_w = (const float*)d_in[1];
    const float* gate_b = (const float*)d_in[2];
    const float* A_w    = (const float*)d_in[3];
    const float* B_w    = (const float*)d_in[4];
    const float* gamma  = (const float*)d_in[5];
    const float* beta   = (const float*)d_in[6];
    float* out = (float*)d_out;
    float* ws  = (float*)d_ws;

    const size_t bd = (size_t)BB * DD;
    // scratch: nslice*B*D partials + B*D delta (floats). Shrink nslice to fit ws.
    int nslice = NSLICE_MAX;
    while (nslice > 1 && (size_t)(nslice + 1) * bd * sizeof(float) > ws_size)
        nslice >>= 1;
    float* partial = ws;
    float* delta   = ws + (size_t)nslice * bd;

    dim3 g1(BB, nslice);
    colsum_kernel<<<g1, 256, 0, stream>>>(
        (const f4*)x, (f4*)partial, LSEQ / nslice);

    router_delta_kernel<<<BB, 1024, 0, stream>>>(
        partial, nslice, gate_w, gate_b, A_w, B_w, delta);

    resid_ln_kernel<<<BB * LSEQ / 4, 256, 0, stream>>>(
        (const f4*)x, (const f4*)delta,
        (const f4*)gamma, (const f4*)beta, (f4*)out);
}